// Round 8
// baseline (1067.332 us; speedup 1.0000x reference)
//
#include <hip/hip_runtime.h>
#include <stdint.h>

#define S_LEN 2048
#define HDIM  2048
#define BATCH 2
#define NKV   8
#define GD    512      // NKV * 64
#define MROWS 4096     // BATCH * S_LEN
#define NQKV  3072     // HDIM + 2*GD

typedef __attribute__((ext_vector_type(8))) __bf16 bf16x8;
typedef __attribute__((ext_vector_type(4))) float f32x4;
typedef __attribute__((ext_vector_type(16))) float f32x16;
typedef unsigned short u16;

// native f32->bf16 (RNE)
__device__ __forceinline__ u16 bfc(float f) {
  union { __bf16 b; u16 u; } v; v.b = (__bf16)f; return v.u;
}
// packed pair convert: one v_cvt_pk_bf16_f32 (T12)
__device__ __forceinline__ int cvtpk(float lo, float hi) {
  int r; asm("v_cvt_pk_bf16_f32 %0, %1, %2" : "=v"(r) : "v"(lo), "v"(hi)); return r;
}

__device__ __forceinline__ void glds16(const void* g, void* lds) {
  __builtin_amdgcn_global_load_lds((const __attribute__((address_space(1))) void*)g,
                                   (__attribute__((address_space(3))) void*)lds, 16, 0, 0);
}

// ---------------- fp32 -> bf16 elementwise convert (vectorized) ----------------
__global__ __launch_bounds__(256) void cvt_f32_bf16_kernel(const float* __restrict__ x,
                                                           u16* __restrict__ y, int n4) {
  int i = blockIdx.x * 256 + threadIdx.x;
  if (i >= n4) return;
  const float4 v = ((const float4*)x)[i];
  ushort4 o;
  o.x = bfc(v.x); o.y = bfc(v.y); o.z = bfc(v.z); o.w = bfc(v.w);
  ((ushort4*)y)[i] = o;
}

// ---------------- bias concat [bq|bk|bv] -> bqkv[3072] ----------------
__global__ __launch_bounds__(256) void concat_bias_kernel(const float* __restrict__ bq,
                                                          const float* __restrict__ bk,
                                                          const float* __restrict__ bv,
                                                          float* __restrict__ o) {
  int i = blockIdx.x * 256 + threadIdx.x;
  if (i < HDIM) o[i] = bq[i];
  else if (i < HDIM + GD) o[i] = bk[i - HDIM];
  else if (i < NQKV) o[i] = bv[i - HDIM - GD];
}

// ---------------- W [Rr,Cc] fp32 -> Wt [Cc,Rr] bf16 (tiled transpose) ----------------
__global__ __launch_bounds__(256) void transpose_f32_bf16(const float* __restrict__ W,
                                                          u16* __restrict__ Wt,
                                                          int Rr, int Cc) {
  __shared__ float t[32][33];
  int bx = blockIdx.x * 32;            // col base in W
  int by = blockIdx.y * 32;            // row base in W
  int tx = threadIdx.x & 31, ty = threadIdx.x >> 5;
#pragma unroll
  for (int i = 0; i < 4; ++i)
    t[ty + i * 8][tx] = W[(size_t)(by + ty + i * 8) * Cc + bx + tx];
  __syncthreads();
#pragma unroll
  for (int i = 0; i < 4; ++i)
    Wt[(size_t)(bx + ty + i * 8) * Rr + by + tx] = bfc(t[tx][ty + i * 8]);
}

// ---------------- v slice of qkv [MROWS,NQKV] -> vT [B,GD,S] bf16 ----------------
__global__ __launch_bounds__(256) void transpose_v_kernel(const u16* __restrict__ QKV,
                                                          u16* __restrict__ Vt) {
  __shared__ u16 t[32][33];
  int b = blockIdx.z;
  const u16* Vb = QKV + (size_t)b * S_LEN * NQKV + HDIM + GD;   // v columns
  u16* Vtb = Vt + (size_t)b * GD * S_LEN;
  int bx = blockIdx.x * 32;            // col in V (0..511)
  int by = blockIdx.y * 32;            // row in V (0..2047)
  int tx = threadIdx.x & 31, ty = threadIdx.x >> 5;
#pragma unroll
  for (int i = 0; i < 4; ++i)
    t[ty + i * 8][tx] = Vb[(size_t)(by + ty + i * 8) * NQKV + bx + tx];
  __syncthreads();
#pragma unroll
  for (int i = 0; i < 4; ++i)
    Vtb[(size_t)(bx + ty + i * 8) * S_LEN + by + tx] = t[tx][ty + i * 8];
}

// ---------------- bf16 GEMM: C[M,N] = (A[M,K] @ Bt[N,K]^T + bias) * alpha(col) ----------------
// T1 bijective XCD swizzle (m204). alpha tile-uniform via qlim (128-aligned).
__global__ __launch_bounds__(256) void gemm_bf16(const u16* __restrict__ A,
                                                 const u16* __restrict__ Bt,
                                                 const float* __restrict__ bias,
                                                 void* __restrict__ C,
                                                 int M, int N, int K,
                                                 float alphaA, float alphaB, int qlim,
                                                 int obf) {
  __shared__ __attribute__((aligned(16))) u16 As[128 * 32];
  __shared__ __attribute__((aligned(16))) u16 Bs[128 * 32];
  const int tid = threadIdx.x, lane = tid & 63, wv = tid >> 6;
  const int wr = wv >> 1, wc = wv & 1;
  const int r16 = lane & 15, kg = lane >> 4;

  // bijective XCD-aware block swizzle
  const int nwg = gridDim.x * gridDim.y;
  const int orig = blockIdx.y * gridDim.x + blockIdx.x;
  const int qq = nwg >> 3, rr = nwg & 7;
  const int xcd = orig & 7, loc = orig >> 3;
  const int swz = (xcd < rr ? xcd * (qq + 1) : rr * (qq + 1) + (xcd - rr) * qq) + loc;
  const int m0 = (swz / gridDim.x) * 128, n0 = (swz % gridDim.x) * 128;
  const float alpha = (n0 < qlim) ? alphaA : alphaB;

  f32x4 acc[4][4];
#pragma unroll
  for (int m = 0; m < 4; ++m)
#pragma unroll
    for (int n = 0; n < 4; ++n) acc[m][n] = (f32x4)0.0f;

  auto stage = [&](int k0) {
#pragma unroll
    for (int i = 0; i < 2; ++i) {
      int chunk = i * 256 + wv * 64 + lane;
      int row = chunk >> 2, cc = chunk & 3;
      glds16(A + (size_t)(m0 + row) * K + k0 + cc * 8, &As[(i * 256 + wv * 64) * 8]);
    }
#pragma unroll
    for (int i = 0; i < 2; ++i) {
      int chunk = i * 256 + wv * 64 + lane;
      int row = chunk >> 2, cc = chunk & 3;
      glds16(Bt + (size_t)(n0 + row) * K + k0 + cc * 8, &Bs[(i * 256 + wv * 64) * 8]);
    }
  };

  stage(0);
  const int nk = K / 32;
  for (int kt = 0; kt < nk; ++kt) {
    asm volatile("s_waitcnt vmcnt(0)" ::: "memory");
    __syncthreads();
    bf16x8 af[4], bfr[4];
#pragma unroll
    for (int m = 0; m < 4; ++m)
      af[m] = *(const bf16x8*)&As[(wr * 64 + m * 16 + r16) * 32 + kg * 8];
#pragma unroll
    for (int n = 0; n < 4; ++n)
      bfr[n] = *(const bf16x8*)&Bs[(wc * 64 + n * 16 + r16) * 32 + kg * 8];
    __syncthreads();
    if (kt + 1 < nk) stage((kt + 1) * 32);
#pragma unroll
    for (int m = 0; m < 4; ++m)
#pragma unroll
      for (int n = 0; n < 4; ++n)
        acc[m][n] = __builtin_amdgcn_mfma_f32_16x16x32_bf16(af[m], bfr[n], acc[m][n], 0, 0, 0);
  }

#pragma unroll
  for (int m = 0; m < 4; ++m) {
    int row = m0 + wr * 64 + m * 16 + kg * 4;
#pragma unroll
    for (int n = 0; n < 4; ++n) {
      int col = n0 + wc * 64 + n * 16 + r16;
      float bb = bias ? bias[col] : 0.0f;
#pragma unroll
      for (int i = 0; i < 4; ++i) {
        float val = (acc[m][n][i] + bb) * alpha;
        if (obf) ((u16*)C)[(size_t)(row + i) * N + col] = bfc(val);
        else     ((float*)C)[(size_t)(row + i) * N + col] = val;
      }
    }
  }
}

// ---------------- fused GQA flash attention (split-K, 2 q-tiles/wave) ----------------
// 8 waves / 512 thr. Waves 0-3 process keys [0,1024), waves 4-7 keys [1024,2048)
// for the SAME 256 queries (wave w: queries w4*64..+64, 2 q-tiles of 32).
// Each 4-wave group owns its own dbuf K/V LDS (64KB total). Shift-free softmax
// (p = exp2(s) raw) makes the partial combine exact: O+=O', l+=l'. l on the
// matrix pipe via ones-B MFMA. Grid 512 = 2 blocks/CU -> 16 waves/CU.
__global__ __launch_bounds__(512, 4) void gqa_attn_kernel(const u16* __restrict__ qkv,
                                                          const u16* __restrict__ vT,
                                                          u16* __restrict__ att) {
  // 64KB: K tiles [grp][buf] at (grp*2+buf)*4096, V tiles at 16384 + same
  __shared__ __attribute__((aligned(16))) u16 smem[32768];

  const int bid = blockIdx.x;
  const int qt = bid & 7;               // 8 q-chunks of 256
  const int h = (bid >> 3) & 31;
  const int b = bid >> 8;
  const int g = h >> 2;                 // R = 4
  const int tid = threadIdx.x, lane = tid & 63, wv = tid >> 6;
  const int grp = wv >> 2, w4 = wv & 3;
  const int q31 = lane & 31, hi = lane >> 5;
  const int qbase = qt * 256 + w4 * 64;
  const int keyoff = grp * 1024;

  // Q fragments for both q-tiles (A: rows qbase+q31, B: +32)
  const u16* qrowA = qkv + (size_t)(b * S_LEN + qbase + q31) * NQKV + h * 64;
  const u16* qrowB = qrowA + (size_t)32 * NQKV;
  bf16x8 qfA[4], qfB[4];
#pragma unroll
  for (int d = 0; d < 4; ++d) {
    qfA[d] = *(const bf16x8*)(qrowA + d * 16 + hi * 8);
    qfB[d] = *(const bf16x8*)(qrowB + d * 16 + hi * 8);
  }

  // ones B-fragment (bf16 1.0 = 0x3F80) for the l-MFMA
  union { u16 w[8]; bf16x8 v; } uo;
#pragma unroll
  for (int i = 0; i < 8; ++i) uo.w[i] = 0x3F80;
  const bf16x8 onesf = uo.v;

  const u16* kbase = qkv + (size_t)(b * S_LEN) * NQKV + HDIM + g * 64;
  const u16* vbase = vT + (size_t)((b * NKV + g) * 64) * S_LEN;

  auto stageK = [&](int t, int buf) {
    const int kk0 = keyoff + t * 64;
    u16* Kd = &smem[(grp * 2 + buf) * 4096];
    u16* Vd = &smem[16384 + (grp * 2 + buf) * 4096];
#pragma unroll
    for (int i = 0; i < 2; ++i) {
      int chunk = i * 256 + w4 * 64 + lane;
      int row = chunk >> 3, cc = chunk & 7;
      int cs = cc ^ (row & 7);          // inverse-swizzled global source chunk
      glds16(kbase + (size_t)(kk0 + row) * NQKV + cs * 8, Kd + (i * 256 + w4 * 64) * 8);
      glds16(vbase + (size_t)row * S_LEN + kk0 + cs * 8, Vd + (i * 256 + w4 * 64) * 8);
    }
  };

  f32x16 o0A = (f32x16)0.0f, o1A = (f32x16)0.0f, olA = (f32x16)0.0f;
  f32x16 o0B = (f32x16)0.0f, o1B = (f32x16)0.0f, olB = (f32x16)0.0f;

  stageK(0, 0);
  int cur = 0;
  const int sw = q31 & 7;               // read-side swizzle (row&7)
  for (int t = 0; t < 16; ++t) {
    asm volatile("s_waitcnt vmcnt(0)" ::: "memory");
    __syncthreads();
    if (t + 1 < 16) stageK(t + 1, cur ^ 1);
    const u16* Kc = &smem[(grp * 2 + cur) * 4096];
    const u16* Vc = &smem[16384 + (grp * 2 + cur) * 4096];

    // ---- QK^T: each kf read feeds 2 MFMAs (q-tiles A,B) ----
    f32x16 pA0 = (f32x16)0.0f, pA1 = (f32x16)0.0f;
    f32x16 pB0 = (f32x16)0.0f, pB1 = (f32x16)0.0f;
    __builtin_amdgcn_s_setprio(1);
#pragma unroll
    for (int d = 0; d < 4; ++d) {
      int ch = ((d * 2 + hi) ^ sw) * 8;
      bf16x8 kf0 = *(const bf16x8*)&Kc[q31 * 64 + ch];
      bf16x8 kf1 = *(const bf16x8*)&Kc[(32 + q31) * 64 + ch];
      pA0 = __builtin_amdgcn_mfma_f32_32x32x16_bf16(kf0, qfA[d], pA0, 0, 0, 0);
      pA1 = __builtin_amdgcn_mfma_f32_32x32x16_bf16(kf1, qfA[d], pA1, 0, 0, 0);
      pB0 = __builtin_amdgcn_mfma_f32_32x32x16_bf16(kf0, qfB[d], pB0, 0, 0, 0);
      pB1 = __builtin_amdgcn_mfma_f32_32x32x16_bf16(kf1, qfB[d], pB1, 0, 0, 0);
    }
    __builtin_amdgcn_s_setprio(0);

    // ---- raw exp2 + in-register pack (cvt_pk + permlane32_swap) ----
#pragma unroll
    for (int r = 0; r < 16; ++r) { pA0[r] = exp2f(pA0[r]); pA1[r] = exp2f(pA1[r]); }
    bf16x8 paA[4], paB[4];
#pragma unroll
    for (int kk = 0; kk < 2; ++kk) {
      int w0 = cvtpk(pA0[kk * 8 + 0], pA0[kk * 8 + 1]);
      int w1 = cvtpk(pA0[kk * 8 + 2], pA0[kk * 8 + 3]);
      int w2 = cvtpk(pA0[kk * 8 + 4], pA0[kk * 8 + 5]);
      int w3 = cvtpk(pA0[kk * 8 + 6], pA0[kk * 8 + 7]);
      auto s0 = __builtin_amdgcn_permlane32_swap(w0, w2, false, false);
      auto s1 = __builtin_amdgcn_permlane32_swap(w1, w3, false, false);
      union { int w[4]; bf16x8 v; } u;
      u.w[0] = s0[0]; u.w[1] = s1[0]; u.w[2] = s0[1]; u.w[3] = s1[1];
      paA[kk] = u.v;
    }
#pragma unroll
    for (int kk = 0; kk < 2; ++kk) {
      int w0 = cvtpk(pA1[kk * 8 + 0], pA1[kk * 8 + 1]);
      int w1 = cvtpk(pA1[kk * 8 + 2], pA1[kk * 8 + 3]);
      int w2 = cvtpk(pA1[kk * 8 + 4], pA1[kk * 8 + 5]);
      int w3 = cvtpk(pA1[kk * 8 + 6], pA1[kk * 8 + 7]);
      auto s0 = __builtin_amdgcn_permlane32_swap(w0, w2, false, false);
      auto s1 = __builtin_amdgcn_permlane32_swap(w1, w3, false, false);
      union { int w[4]; bf16x8 v; } u;
      u.w[0] = s0[0]; u.w[1] = s1[0]; u.w[2] = s0[1]; u.w[3] = s1[1];
      paA[2 + kk] = u.v;
    }
#pragma unroll
    for (int r = 0; r < 16; ++r) { pB0[r] = exp2f(pB0[r]); pB1[r] = exp2f(pB1[r]); }
#pragma unroll
    for (int kk = 0; kk < 2; ++kk) {
      int w0 = cvtpk(pB0[kk * 8 + 0], pB0[kk * 8 + 1]);
      int w1 = cvtpk(pB0[kk * 8 + 2], pB0[kk * 8 + 3]);
      int w2 = cvtpk(pB0[kk * 8 + 4], pB0[kk * 8 + 5]);
      int w3 = cvtpk(pB0[kk * 8 + 6], pB0[kk * 8 + 7]);
      auto s0 = __builtin_amdgcn_permlane32_swap(w0, w2, false, false);
      auto s1 = __builtin_amdgcn_permlane32_swap(w1, w3, false, false);
      union { int w[4]; bf16x8 v; } u;
      u.w[0] = s0[0]; u.w[1] = s1[0]; u.w[2] = s0[1]; u.w[3] = s1[1];
      paB[kk] = u.v;
    }
#pragma unroll
    for (int kk = 0; kk < 2; ++kk) {
      int w0 = cvtpk(pB1[kk * 8 + 0], pB1[kk * 8 + 1]);
      int w1 = cvtpk(pB1[kk * 8 + 2], pB1[kk * 8 + 3]);
      int w2 = cvtpk(pB1[kk * 8 + 4], pB1[kk * 8 + 5]);
      int w3 = cvtpk(pB1[kk * 8 + 6], pB1[kk * 8 + 7]);
      auto s0 = __builtin_amdgcn_permlane32_swap(w0, w2, false, false);
      auto s1 = __builtin_amdgcn_permlane32_swap(w1, w3, false, false);
      union { int w[4]; bf16x8 v; } u;
      u.w[0] = s0[0]; u.w[1] = s1[0]; u.w[2] = s0[1]; u.w[3] = s1[1];
      paB[2 + kk] = u.v;
    }

    // ---- PV: each vf read feeds 2 O-MFMAs; l via ones-MFMA ----
    __builtin_amdgcn_s_setprio(1);
#pragma unroll
    for (int ks = 0; ks < 4; ++ks) {
      int ch = ((ks * 2 + hi) ^ sw) * 8;
      bf16x8 vf0 = *(const bf16x8*)&Vc[q31 * 64 + ch];
      bf16x8 vf1 = *(const bf16x8*)&Vc[(32 + q31) * 64 + ch];
      o0A = __builtin_amdgcn_mfma_f32_32x32x16_bf16(paA[ks], vf0, o0A, 0, 0, 0);
      o1A = __builtin_amdgcn_mfma_f32_32x32x16_bf16(paA[ks], vf1, o1A, 0, 0, 0);
      o0B = __builtin_amdgcn_mfma_f32_32x32x16_bf16(paB[ks], vf0, o0B, 0, 0, 0);
      o1B = __builtin_amdgcn_mfma_f32_32x32x16_bf16(paB[ks], vf1, o1B, 0, 0, 0);
      olA = __builtin_amdgcn_mfma_f32_32x32x16_bf16(paA[ks], onesf, olA, 0, 0, 0);
      olB = __builtin_amdgcn_mfma_f32_32x32x16_bf16(paB[ks], onesf, olB, 0, 0, 0);
    }
    __builtin_amdgcn_s_setprio(0);
    cur ^= 1;
  }

  // ---- split-K combine: grp1 partials added into grp0 via LDS (2 rounds) ----
  float* fb = (float*)smem;
  const int idx = (w4 * 64 + lane) * 48;
  __syncthreads();
  if (grp == 1) {
#pragma unroll
    for (int r = 0; r < 16; ++r) {
      fb[idx + r] = o0A[r]; fb[idx + 16 + r] = o1A[r]; fb[idx + 32 + r] = olA[r];
    }
  }
  __syncthreads();
  if (grp == 0) {
#pragma unroll
    for (int r = 0; r < 16; ++r) {
      o0A[r] += fb[idx + r]; o1A[r] += fb[idx + 16 + r]; olA[r] += fb[idx + 32 + r];
    }
  }
  __syncthreads();
  if (grp == 1) {
#pragma unroll
    for (int r = 0; r < 16; ++r) {
      fb[idx + r] = o0B[r]; fb[idx + 16 + r] = o1B[r]; fb[idx + 32 + r] = olB[r];
    }
  }
  __syncthreads();
  if (grp == 0) {
#pragma unroll
    for (int r = 0; r < 16; ++r) {
      o0B[r] += fb[idx + r]; o1B[r] += fb[idx + 16 + r]; olB[r] += fb[idx + 32 + r];
    }
    // ---- finalize: every lane holds its rows' l ----
    u16* obase = att + (size_t)(b * S_LEN + qbase) * HDIM + h * 64 + q31;
#pragma unroll
    for (int r = 0; r < 16; ++r) {
      int qq = (r & 3) + 8 * (r >> 2) + 4 * hi;
      float invA = 1.0f / olA[r];
      float invB = 1.0f / olB[r];
      obase[(size_t)qq * HDIM]             = bfc(o0A[r] * invA);
      obase[(size_t)qq * HDIM + 32]        = bfc(o1A[r] * invA);
      obase[(size_t)(qq + 32) * HDIM]      = bfc(o0B[r] * invB);
      obase[(size_t)(qq + 32) * HDIM + 32] = bfc(o1B[r] * invB);
    }
  }
}

extern "C" void kernel_launch(void* const* d_in, const int* in_sizes, int n_in,
                              void* d_out, int out_size, void* d_ws, size_t ws_size,
                              hipStream_t stream) {
  const float* x  = (const float*)d_in[0];
  const float* Wq = (const float*)d_in[1];
  const float* bq = (const float*)d_in[2];
  const float* Wk = (const float*)d_in[3];
  const float* bk = (const float*)d_in[4];
  const float* Wv = (const float*)d_in[5];
  const float* bv = (const float*)d_in[6];
  const float* Wo = (const float*)d_in[7];
  const float* bo = (const float*)d_in[8];
  float* out = (float*)d_out;

  char* p = (char*)d_ws;
  u16* xb    = (u16*)p; p += (size_t)MROWS * HDIM * 2;
  u16* wqkvT = (u16*)p; p += (size_t)NQKV * HDIM * 2;     // [3072 x 2048] bf16
  u16* woT   = (u16*)p; p += (size_t)HDIM * HDIM * 2;
  float* bqkv = (float*)p; p += (size_t)NQKV * 4;
  u16* qkv   = (u16*)p; p += (size_t)MROWS * NQKV * 2;    // [4096 x 3072] bf16
  u16* vtb   = (u16*)p; p += (size_t)MROWS * GD * 2;
  u16* attb  = (u16*)p; p += (size_t)MROWS * HDIM * 2;

  const float aQ = 0.18033688011112042f;  // (1/sqrt(64)) * log2(e)

  // convert x to bf16
  cvt_f32_bf16_kernel<<<(MROWS * HDIM / 4 + 255) / 256, 256, 0, stream>>>(x, xb, MROWS * HDIM / 4);
  // transpose+convert weights into stacked [3072,2048] bf16 (Q rows 0-2047, K 2048-2559, V 2560-3071)
  transpose_f32_bf16<<<dim3(HDIM / 32, HDIM / 32), 256, 0, stream>>>(Wq, wqkvT, HDIM, HDIM);
  transpose_f32_bf16<<<dim3(GD / 32, HDIM / 32), 256, 0, stream>>>(Wk, wqkvT + (size_t)HDIM * HDIM, HDIM, GD);
  transpose_f32_bf16<<<dim3(GD / 32, HDIM / 32), 256, 0, stream>>>(Wv, wqkvT + (size_t)(HDIM + GD) * HDIM, HDIM, GD);
  transpose_f32_bf16<<<dim3(HDIM / 32, HDIM / 32), 256, 0, stream>>>(Wo, woT, HDIM, HDIM);
  concat_bias_kernel<<<(NQKV + 255) / 256, 256, 0, stream>>>(bq, bk, bv, bqkv);
  // fused QKV projection: [4096,2048] @ [3072,2048]^T; Q cols scaled by aQ
  gemm_bf16<<<dim3(NQKV / 128, MROWS / 128), 256, 0, stream>>>(xb, wqkvT, bqkv, qkv,
                                                               MROWS, NQKV, HDIM, aQ, 1.0f, HDIM, 1);
  // V -> V^T per batch
  transpose_v_kernel<<<dim3(GD / 32, S_LEN / 32, BATCH), 256, 0, stream>>>(qkv, vtb);
  // fused attention: B * NH * (S/256) blocks of 8 waves (split-K, 2 blocks/CU)
  gqa_attn_kernel<<<BATCH * 32 * 8, 512, 0, stream>>>(qkv, vtb, attb);
  // output projection -> fp32 out
  gemm_bf16<<<dim3(HDIM / 128, MROWS / 128), 256, 0, stream>>>(attb, woT, bo, out,
                                                               MROWS, HDIM, HDIM, 1.0f, 1.0f, HDIM, 0);
}

// Round 9
// 242.628 us; speedup vs baseline: 4.3991x; 4.3991x over previous
//
#include <hip/hip_runtime.h>
#include <stdint.h>

#define S_LEN 2048
#define HDIM  2048
#define BATCH 2
#define NKV   8
#define GD    512      // NKV * 64
#define MROWS 4096     // BATCH * S_LEN
#define NQKV  3072     // HDIM + 2*GD

typedef __attribute__((ext_vector_type(8))) __bf16 bf16x8;
typedef __attribute__((ext_vector_type(4))) float f32x4;
typedef __attribute__((ext_vector_type(16))) float f32x16;
typedef unsigned short u16;

// native f32->bf16 (RNE)
__device__ __forceinline__ u16 bfc(float f) {
  union { __bf16 b; u16 u; } v; v.b = (__bf16)f; return v.u;
}
// packed pair convert: one v_cvt_pk_bf16_f32 (T12)
__device__ __forceinline__ int cvtpk(float lo, float hi) {
  int r; asm("v_cvt_pk_bf16_f32 %0, %1, %2" : "=v"(r) : "v"(lo), "v"(hi)); return r;
}

__device__ __forceinline__ void glds16(const void* g, void* lds) {
  __builtin_amdgcn_global_load_lds((const __attribute__((address_space(1))) void*)g,
                                   (__attribute__((address_space(3))) void*)lds, 16, 0, 0);
}

// ---------------- fp32 -> bf16 elementwise convert (vectorized) ----------------
__global__ __launch_bounds__(256) void cvt_f32_bf16_kernel(const float* __restrict__ x,
                                                           u16* __restrict__ y, int n4) {
  int i = blockIdx.x * 256 + threadIdx.x;
  if (i >= n4) return;
  const float4 v = ((const float4*)x)[i];
  ushort4 o;
  o.x = bfc(v.x); o.y = bfc(v.y); o.z = bfc(v.z); o.w = bfc(v.w);
  ((ushort4*)y)[i] = o;
}

// ---------------- bias concat [bq|bk|bv] -> bqkv[3072] ----------------
__global__ __launch_bounds__(256) void concat_bias_kernel(const float* __restrict__ bq,
                                                          const float* __restrict__ bk,
                                                          const float* __restrict__ bv,
                                                          float* __restrict__ o) {
  int i = blockIdx.x * 256 + threadIdx.x;
  if (i < HDIM) o[i] = bq[i];
  else if (i < HDIM + GD) o[i] = bk[i - HDIM];
  else if (i < NQKV) o[i] = bv[i - HDIM - GD];
}

// ---------------- W [Rr,Cc] fp32 -> Wt [Cc,Rr] bf16 (tiled transpose) ----------------
__global__ __launch_bounds__(256) void transpose_f32_bf16(const float* __restrict__ W,
                                                          u16* __restrict__ Wt,
                                                          int Rr, int Cc) {
  __shared__ float t[32][33];
  int bx = blockIdx.x * 32;            // col base in W
  int by = blockIdx.y * 32;            // row base in W
  int tx = threadIdx.x & 31, ty = threadIdx.x >> 5;
#pragma unroll
  for (int i = 0; i < 4; ++i)
    t[ty + i * 8][tx] = W[(size_t)(by + ty + i * 8) * Cc + bx + tx];
  __syncthreads();
#pragma unroll
  for (int i = 0; i < 4; ++i)
    Wt[(size_t)(bx + ty + i * 8) * Rr + by + tx] = bfc(t[tx][ty + i * 8]);
}

// ---------------- v slice of qkv [MROWS,NQKV] -> vT [B,GD,S] bf16 ----------------
__global__ __launch_bounds__(256) void transpose_v_kernel(const u16* __restrict__ QKV,
                                                          u16* __restrict__ Vt) {
  __shared__ u16 t[32][33];
  int b = blockIdx.z;
  const u16* Vb = QKV + (size_t)b * S_LEN * NQKV + HDIM + GD;   // v columns
  u16* Vtb = Vt + (size_t)b * GD * S_LEN;
  int bx = blockIdx.x * 32;            // col in V (0..511)
  int by = blockIdx.y * 32;            // row in V (0..2047)
  int tx = threadIdx.x & 31, ty = threadIdx.x >> 5;
#pragma unroll
  for (int i = 0; i < 4; ++i)
    t[ty + i * 8][tx] = Vb[(size_t)(by + ty + i * 8) * NQKV + bx + tx];
  __syncthreads();
#pragma unroll
  for (int i = 0; i < 4; ++i)
    Vtb[(size_t)(bx + ty + i * 8) * S_LEN + by + tx] = t[tx][ty + i * 8];
}

// ---------------- bf16 GEMM: C[M,N] = (A[M,K] @ Bt[N,K]^T + bias) * alpha(col) ----------------
// T1 bijective XCD swizzle (m204). alpha tile-uniform via qlim (128-aligned).
__global__ __launch_bounds__(256) void gemm_bf16(const u16* __restrict__ A,
                                                 const u16* __restrict__ Bt,
                                                 const float* __restrict__ bias,
                                                 void* __restrict__ C,
                                                 int M, int N, int K,
                                                 float alphaA, float alphaB, int qlim,
                                                 int obf) {
  __shared__ __attribute__((aligned(16))) u16 As[128 * 32];
  __shared__ __attribute__((aligned(16))) u16 Bs[128 * 32];
  const int tid = threadIdx.x, lane = tid & 63, wv = tid >> 6;
  const int wr = wv >> 1, wc = wv & 1;
  const int r16 = lane & 15, kg = lane >> 4;

  // bijective XCD-aware block swizzle
  const int nwg = gridDim.x * gridDim.y;
  const int orig = blockIdx.y * gridDim.x + blockIdx.x;
  const int qq = nwg >> 3, rr = nwg & 7;
  const int xcd = orig & 7, loc = orig >> 3;
  const int swz = (xcd < rr ? xcd * (qq + 1) : rr * (qq + 1) + (xcd - rr) * qq) + loc;
  const int m0 = (swz / gridDim.x) * 128, n0 = (swz % gridDim.x) * 128;
  const float alpha = (n0 < qlim) ? alphaA : alphaB;

  f32x4 acc[4][4];
#pragma unroll
  for (int m = 0; m < 4; ++m)
#pragma unroll
    for (int n = 0; n < 4; ++n) acc[m][n] = (f32x4)0.0f;

  auto stage = [&](int k0) {
#pragma unroll
    for (int i = 0; i < 2; ++i) {
      int chunk = i * 256 + wv * 64 + lane;
      int row = chunk >> 2, cc = chunk & 3;
      glds16(A + (size_t)(m0 + row) * K + k0 + cc * 8, &As[(i * 256 + wv * 64) * 8]);
    }
#pragma unroll
    for (int i = 0; i < 2; ++i) {
      int chunk = i * 256 + wv * 64 + lane;
      int row = chunk >> 2, cc = chunk & 3;
      glds16(Bt + (size_t)(n0 + row) * K + k0 + cc * 8, &Bs[(i * 256 + wv * 64) * 8]);
    }
  };

  stage(0);
  const int nk = K / 32;
  for (int kt = 0; kt < nk; ++kt) {
    asm volatile("s_waitcnt vmcnt(0)" ::: "memory");
    __syncthreads();
    bf16x8 af[4], bfr[4];
#pragma unroll
    for (int m = 0; m < 4; ++m)
      af[m] = *(const bf16x8*)&As[(wr * 64 + m * 16 + r16) * 32 + kg * 8];
#pragma unroll
    for (int n = 0; n < 4; ++n)
      bfr[n] = *(const bf16x8*)&Bs[(wc * 64 + n * 16 + r16) * 32 + kg * 8];
    __syncthreads();
    if (kt + 1 < nk) stage((kt + 1) * 32);
#pragma unroll
    for (int m = 0; m < 4; ++m)
#pragma unroll
      for (int n = 0; n < 4; ++n)
        acc[m][n] = __builtin_amdgcn_mfma_f32_16x16x32_bf16(af[m], bfr[n], acc[m][n], 0, 0, 0);
  }

#pragma unroll
  for (int m = 0; m < 4; ++m) {
    int row = m0 + wr * 64 + m * 16 + kg * 4;
#pragma unroll
    for (int n = 0; n < 4; ++n) {
      int col = n0 + wc * 64 + n * 16 + r16;
      float bb = bias ? bias[col] : 0.0f;
#pragma unroll
      for (int i = 0; i < 4; ++i) {
        float val = (acc[m][n][i] + bb) * alpha;
        if (obf) ((u16*)C)[(size_t)(row + i) * N + col] = bfc(val);
        else     ((float*)C)[(size_t)(row + i) * N + col] = val;
      }
    }
  }
}

// ---------------- fused GQA flash attention (split-K, 2 q-tiles/wave) ----------------
// 8 waves / 512 thr. Waves 0-3 process keys [0,1024), waves 4-7 keys [1024,2048)
// for the SAME 256 queries. Each 4-wave group owns its own dbuf K/V LDS (64KB).
// Shift-free softmax -> exact partial combine: O+=O', l+=l'. l on the matrix
// pipe via ones-B MFMA. launch_bounds(512,2): 256-reg combined budget, NO SPILL
// (R8's (512,4) forced a 128-reg budget -> 2.8GB scratch traffic).
__global__ __launch_bounds__(512, 2) void gqa_attn_kernel(const u16* __restrict__ qkv,
                                                          const u16* __restrict__ vT,
                                                          u16* __restrict__ att) {
  // 64KB: K tiles [grp][buf] at (grp*2+buf)*4096, V tiles at 16384 + same
  __shared__ __attribute__((aligned(16))) u16 smem[32768];

  const int bid = blockIdx.x;
  const int qt = bid & 7;               // 8 q-chunks of 256
  const int h = (bid >> 3) & 31;
  const int b = bid >> 8;
  const int g = h >> 2;                 // R = 4
  const int tid = threadIdx.x, lane = tid & 63, wv = tid >> 6;
  const int grp = wv >> 2, w4 = wv & 3;
  const int q31 = lane & 31, hi = lane >> 5;
  const int qbase = qt * 256 + w4 * 64;
  const int keyoff = grp * 1024;

  // Q fragments for both q-tiles (A: rows qbase+q31, B: +32)
  const u16* qrowA = qkv + (size_t)(b * S_LEN + qbase + q31) * NQKV + h * 64;
  const u16* qrowB = qrowA + (size_t)32 * NQKV;
  bf16x8 qfA[4], qfB[4];
#pragma unroll
  for (int d = 0; d < 4; ++d) {
    qfA[d] = *(const bf16x8*)(qrowA + d * 16 + hi * 8);
    qfB[d] = *(const bf16x8*)(qrowB + d * 16 + hi * 8);
  }

  // ones B-fragment (bf16 1.0 = 0x3F80) for the l-MFMA
  union { u16 w[8]; bf16x8 v; } uo;
#pragma unroll
  for (int i = 0; i < 8; ++i) uo.w[i] = 0x3F80;
  const bf16x8 onesf = uo.v;

  const u16* kbase = qkv + (size_t)(b * S_LEN) * NQKV + HDIM + g * 64;
  const u16* vbase = vT + (size_t)((b * NKV + g) * 64) * S_LEN;

  auto stageK = [&](int t, int buf) {
    const int kk0 = keyoff + t * 64;
    u16* Kd = &smem[(grp * 2 + buf) * 4096];
    u16* Vd = &smem[16384 + (grp * 2 + buf) * 4096];
#pragma unroll
    for (int i = 0; i < 2; ++i) {
      int chunk = i * 256 + w4 * 64 + lane;
      int row = chunk >> 3, cc = chunk & 7;
      int cs = cc ^ (row & 7);          // inverse-swizzled global source chunk
      glds16(kbase + (size_t)(kk0 + row) * NQKV + cs * 8, Kd + (i * 256 + w4 * 64) * 8);
      glds16(vbase + (size_t)row * S_LEN + kk0 + cs * 8, Vd + (i * 256 + w4 * 64) * 8);
    }
  };

  f32x16 o0A = (f32x16)0.0f, o1A = (f32x16)0.0f, olA = (f32x16)0.0f;
  f32x16 o0B = (f32x16)0.0f, o1B = (f32x16)0.0f, olB = (f32x16)0.0f;

  stageK(0, 0);
  int cur = 0;
  const int sw = q31 & 7;               // read-side swizzle (row&7)
  for (int t = 0; t < 16; ++t) {
    asm volatile("s_waitcnt vmcnt(0)" ::: "memory");
    __syncthreads();
    if (t + 1 < 16) stageK(t + 1, cur ^ 1);
    const u16* Kc = &smem[(grp * 2 + cur) * 4096];
    const u16* Vc = &smem[16384 + (grp * 2 + cur) * 4096];

    // ---- QK^T: each kf read feeds 2 MFMAs (q-tiles A,B) ----
    f32x16 pA0 = (f32x16)0.0f, pA1 = (f32x16)0.0f;
    f32x16 pB0 = (f32x16)0.0f, pB1 = (f32x16)0.0f;
    __builtin_amdgcn_s_setprio(1);
#pragma unroll
    for (int d = 0; d < 4; ++d) {
      int ch = ((d * 2 + hi) ^ sw) * 8;
      bf16x8 kf0 = *(const bf16x8*)&Kc[q31 * 64 + ch];
      bf16x8 kf1 = *(const bf16x8*)&Kc[(32 + q31) * 64 + ch];
      pA0 = __builtin_amdgcn_mfma_f32_32x32x16_bf16(kf0, qfA[d], pA0, 0, 0, 0);
      pA1 = __builtin_amdgcn_mfma_f32_32x32x16_bf16(kf1, qfA[d], pA1, 0, 0, 0);
      pB0 = __builtin_amdgcn_mfma_f32_32x32x16_bf16(kf0, qfB[d], pB0, 0, 0, 0);
      pB1 = __builtin_amdgcn_mfma_f32_32x32x16_bf16(kf1, qfB[d], pB1, 0, 0, 0);
    }
    __builtin_amdgcn_s_setprio(0);

    // ---- raw exp2 + in-register pack (cvt_pk + permlane32_swap) ----
#pragma unroll
    for (int r = 0; r < 16; ++r) { pA0[r] = exp2f(pA0[r]); pA1[r] = exp2f(pA1[r]); }
    bf16x8 paA[4], paB[4];
#pragma unroll
    for (int kk = 0; kk < 2; ++kk) {
      int w0 = cvtpk(pA0[kk * 8 + 0], pA0[kk * 8 + 1]);
      int w1 = cvtpk(pA0[kk * 8 + 2], pA0[kk * 8 + 3]);
      int w2 = cvtpk(pA0[kk * 8 + 4], pA0[kk * 8 + 5]);
      int w3 = cvtpk(pA0[kk * 8 + 6], pA0[kk * 8 + 7]);
      auto s0 = __builtin_amdgcn_permlane32_swap(w0, w2, false, false);
      auto s1 = __builtin_amdgcn_permlane32_swap(w1, w3, false, false);
      union { int w[4]; bf16x8 v; } u;
      u.w[0] = s0[0]; u.w[1] = s1[0]; u.w[2] = s0[1]; u.w[3] = s1[1];
      paA[kk] = u.v;
    }
#pragma unroll
    for (int kk = 0; kk < 2; ++kk) {
      int w0 = cvtpk(pA1[kk * 8 + 0], pA1[kk * 8 + 1]);
      int w1 = cvtpk(pA1[kk * 8 + 2], pA1[kk * 8 + 3]);
      int w2 = cvtpk(pA1[kk * 8 + 4], pA1[kk * 8 + 5]);
      int w3 = cvtpk(pA1[kk * 8 + 6], pA1[kk * 8 + 7]);
      auto s0 = __builtin_amdgcn_permlane32_swap(w0, w2, false, false);
      auto s1 = __builtin_amdgcn_permlane32_swap(w1, w3, false, false);
      union { int w[4]; bf16x8 v; } u;
      u.w[0] = s0[0]; u.w[1] = s1[0]; u.w[2] = s0[1]; u.w[3] = s1[1];
      paA[2 + kk] = u.v;
    }
#pragma unroll
    for (int r = 0; r < 16; ++r) { pB0[r] = exp2f(pB0[r]); pB1[r] = exp2f(pB1[r]); }
#pragma unroll
    for (int kk = 0; kk < 2; ++kk) {
      int w0 = cvtpk(pB0[kk * 8 + 0], pB0[kk * 8 + 1]);
      int w1 = cvtpk(pB0[kk * 8 + 2], pB0[kk * 8 + 3]);
      int w2 = cvtpk(pB0[kk * 8 + 4], pB0[kk * 8 + 5]);
      int w3 = cvtpk(pB0[kk * 8 + 6], pB0[kk * 8 + 7]);
      auto s0 = __builtin_amdgcn_permlane32_swap(w0, w2, false, false);
      auto s1 = __builtin_amdgcn_permlane32_swap(w1, w3, false, false);
      union { int w[4]; bf16x8 v; } u;
      u.w[0] = s0[0]; u.w[1] = s1[0]; u.w[2] = s0[1]; u.w[3] = s1[1];
      paB[kk] = u.v;
    }
#pragma unroll
    for (int kk = 0; kk < 2; ++kk) {
      int w0 = cvtpk(pB1[kk * 8 + 0], pB1[kk * 8 + 1]);
      int w1 = cvtpk(pB1[kk * 8 + 2], pB1[kk * 8 + 3]);
      int w2 = cvtpk(pB1[kk * 8 + 4], pB1[kk * 8 + 5]);
      int w3 = cvtpk(pB1[kk * 8 + 6], pB1[kk * 8 + 7]);
      auto s0 = __builtin_amdgcn_permlane32_swap(w0, w2, false, false);
      auto s1 = __builtin_amdgcn_permlane32_swap(w1, w3, false, false);
      union { int w[4]; bf16x8 v; } u;
      u.w[0] = s0[0]; u.w[1] = s1[0]; u.w[2] = s0[1]; u.w[3] = s1[1];
      paB[2 + kk] = u.v;
    }

    // ---- PV: each vf read feeds 2 O-MFMAs; l via ones-MFMA ----
    __builtin_amdgcn_s_setprio(1);
#pragma unroll
    for (int ks = 0; ks < 4; ++ks) {
      int ch = ((ks * 2 + hi) ^ sw) * 8;
      bf16x8 vf0 = *(const bf16x8*)&Vc[q31 * 64 + ch];
      bf16x8 vf1 = *(const bf16x8*)&Vc[(32 + q31) * 64 + ch];
      o0A = __builtin_amdgcn_mfma_f32_32x32x16_bf16(paA[ks], vf0, o0A, 0, 0, 0);
      o1A = __builtin_amdgcn_mfma_f32_32x32x16_bf16(paA[ks], vf1, o1A, 0, 0, 0);
      o0B = __builtin_amdgcn_mfma_f32_32x32x16_bf16(paB[ks], vf0, o0B, 0, 0, 0);
      o1B = __builtin_amdgcn_mfma_f32_32x32x16_bf16(paB[ks], vf1, o1B, 0, 0, 0);
      olA = __builtin_amdgcn_mfma_f32_32x32x16_bf16(paA[ks], onesf, olA, 0, 0, 0);
      olB = __builtin_amdgcn_mfma_f32_32x32x16_bf16(paB[ks], onesf, olB, 0, 0, 0);
    }
    __builtin_amdgcn_s_setprio(0);
    cur ^= 1;
  }

  // ---- split-K combine: grp1 partials added into grp0 via LDS (2 rounds) ----
  float* fb = (float*)smem;
  const int idx = (w4 * 64 + lane) * 48;
  __syncthreads();
  if (grp == 1) {
#pragma unroll
    for (int r = 0; r < 16; ++r) {
      fb[idx + r] = o0A[r]; fb[idx + 16 + r] = o1A[r]; fb[idx + 32 + r] = olA[r];
    }
  }
  __syncthreads();
  if (grp == 0) {
#pragma unroll
    for (int r = 0; r < 16; ++r) {
      o0A[r] += fb[idx + r]; o1A[r] += fb[idx + 16 + r]; olA[r] += fb[idx + 32 + r];
    }
  }
  __syncthreads();
  if (grp == 1) {
#pragma unroll
    for (int r = 0; r < 16; ++r) {
      fb[idx + r] = o0B[r]; fb[idx + 16 + r] = o1B[r]; fb[idx + 32 + r] = olB[r];
    }
  }
  __syncthreads();
  if (grp == 0) {
#pragma unroll
    for (int r = 0; r < 16; ++r) {
      o0B[r] += fb[idx + r]; o1B[r] += fb[idx + 16 + r]; olB[r] += fb[idx + 32 + r];
    }
    // ---- finalize: every lane holds its rows' l ----
    u16* obase = att + (size_t)(b * S_LEN + qbase) * HDIM + h * 64 + q31;
#pragma unroll
    for (int r = 0; r < 16; ++r) {
      int qq = (r & 3) + 8 * (r >> 2) + 4 * hi;
      float invA = 1.0f / olA[r];
      float invB = 1.0f / olB[r];
      obase[(size_t)qq * HDIM]             = bfc(o0A[r] * invA);
      obase[(size_t)qq * HDIM + 32]        = bfc(o1A[r] * invA);
      obase[(size_t)(qq + 32) * HDIM]      = bfc(o0B[r] * invB);
      obase[(size_t)(qq + 32) * HDIM + 32] = bfc(o1B[r] * invB);
    }
  }
}

extern "C" void kernel_launch(void* const* d_in, const int* in_sizes, int n_in,
                              void* d_out, int out_size, void* d_ws, size_t ws_size,
                              hipStream_t stream) {
  const float* x  = (const float*)d_in[0];
  const float* Wq = (const float*)d_in[1];
  const float* bq = (const float*)d_in[2];
  const float* Wk = (const float*)d_in[3];
  const float* bk = (const float*)d_in[4];
  const float* Wv = (const float*)d_in[5];
  const float* bv = (const float*)d_in[6];
  const float* Wo = (const float*)d_in[7];
  const float* bo = (const float*)d_in[8];
  float* out = (float*)d_out;

  char* p = (char*)d_ws;
  u16* xb    = (u16*)p; p += (size_t)MROWS * HDIM * 2;
  u16* wqkvT = (u16*)p; p += (size_t)NQKV * HDIM * 2;     // [3072 x 2048] bf16
  u16* woT   = (u16*)p; p += (size_t)HDIM * HDIM * 2;
  float* bqkv = (float*)p; p += (size_t)NQKV * 4;
  u16* qkv   = (u16*)p; p += (size_t)MROWS * NQKV * 2;    // [4096 x 3072] bf16
  u16* vtb   = (u16*)p; p += (size_t)MROWS * GD * 2;
  u16* attb  = (u16*)p; p += (size_t)MROWS * HDIM * 2;

  const float aQ = 0.18033688011112042f;  // (1/sqrt(64)) * log2(e)

  // convert x to bf16
  cvt_f32_bf16_kernel<<<(MROWS * HDIM / 4 + 255) / 256, 256, 0, stream>>>(x, xb, MROWS * HDIM / 4);
  // transpose+convert weights into stacked [3072,2048] bf16 (Q rows 0-2047, K 2048-2559, V 2560-3071)
  transpose_f32_bf16<<<dim3(HDIM / 32, HDIM / 32), 256, 0, stream>>>(Wq, wqkvT, HDIM, HDIM);
  transpose_f32_bf16<<<dim3(GD / 32, HDIM / 32), 256, 0, stream>>>(Wk, wqkvT + (size_t)HDIM * HDIM, HDIM, GD);
  transpose_f32_bf16<<<dim3(GD / 32, HDIM / 32), 256, 0, stream>>>(Wv, wqkvT + (size_t)(HDIM + GD) * HDIM, HDIM, GD);
  transpose_f32_bf16<<<dim3(HDIM / 32, HDIM / 32), 256, 0, stream>>>(Wo, woT, HDIM, HDIM);
  concat_bias_kernel<<<(NQKV + 255) / 256, 256, 0, stream>>>(bq, bk, bv, bqkv);
  // fused QKV projection: [4096,2048] @ [3072,2048]^T; Q cols scaled by aQ
  gemm_bf16<<<dim3(NQKV / 128, MROWS / 128), 256, 0, stream>>>(xb, wqkvT, bqkv, qkv,
                                                               MROWS, NQKV, HDIM, aQ, 1.0f, HDIM, 1);
  // V -> V^T per batch
  transpose_v_kernel<<<dim3(GD / 32, S_LEN / 32, BATCH), 256, 0, stream>>>(qkv, vtb);
  // fused attention: B * NH * (S/256) blocks of 8 waves (split-K, 2 blocks/CU)
  gqa_attn_kernel<<<BATCH * 32 * 8, 512, 0, stream>>>(qkv, vtb, attb);
  // output projection -> fp32 out
  gemm_bf16<<<dim3(HDIM / 128, MROWS / 128), 256, 0, stream>>>(attb, woT, bo, out,
                                                               MROWS, HDIM, HDIM, 1.0f, 1.0f, HDIM, 0);
}